// Round 3
// baseline (6612.772 us; speedup 1.0000x reference)
//
#include <hip/hip_runtime.h>

// Problem constants
#define NROWS 16384      // 8 * (8*16*16)
#define NE 8192
#define KSPL 4
#define KPER (NE / KSPL) // 2048
#define OUT_LOSS 4194304
#define OUT_IDX  4194305

// ---------------- S1[n] = np.sum(zf*zf, axis=1) bit-exact emulation ----------------
// numpy pairwise_sum over 256 contiguous fp32: split 128+128; each 128-block:
// 8 accumulators r[j] += w[8t+j] (t ascending), tree ((r0+r1)+(r2+r3))+((r4+r5)+(r6+r7));
// final S1 = blk0 + blk1. All fp32, no fma, no reassociation.
__global__ void k_s1(const float* __restrict__ Z, float* __restrict__ S1) {
#pragma clang fp contract(off)
    const int n = blockIdx.x * 256 + threadIdx.x;
    const int b = n >> 11, m = n & 2047;
    const float* zp = Z + b * 524288 + m;   // element c at zp[c*2048]
    float blk[2];
#pragma unroll
    for (int h = 0; h < 2; ++h) {
        float r[8];
#pragma unroll
        for (int j = 0; j < 8; ++j) {
            float z = zp[(h * 128 + j) * 2048];
            float w = z * z;
            asm("" : "+v"(w));
            r[j] = w;
        }
        for (int t2 = 1; t2 < 16; ++t2) {
#pragma unroll
            for (int j = 0; j < 8; ++j) {
                float z = zp[(h * 128 + t2 * 8 + j) * 2048];
                float w = z * z;
                asm("" : "+v"(w));
                r[j] += w;
            }
        }
        float s01 = r[0] + r[1], s23 = r[2] + r[3];
        float s45 = r[4] + r[5], s67 = r[6] + r[7];
        blk[h] = (s01 + s23) + (s45 + s67);
    }
    S1[n] = blk[0] + blk[1];
}

// ---------------- np-fp32-emulated argmin over k ----------------
// P[n,k] emulates numpy einsum contig_contig_outstride0_two (SSE 4-lane, no FMA):
// lane j of a 4-lane group owns chain A_j = sequential fp32 sum of z[c]*e[c], c = j mod 4;
// P = fl(fl(A0+A1) + fl(A2+A3)). dist = fl(S1 - 2*P)  (S2 absorbed: < 0.5 ulp(S1)).
// Strict < scan, k ascending -> first-occurrence argmin per k-split.
__launch_bounds__(256, 3)
__global__ void k_np(const float* __restrict__ Z, const float* __restrict__ E,
                     const float* __restrict__ S1, float2* __restrict__ part) {
#pragma clang fp contract(off)
    const int t = threadIdx.x;
    const int j = t & 3;                 // np SIMD lane (c mod 4)
    const int rb = blockIdx.x & 255;     // row-block (64 rows)
    const int ks = blockIdx.x >> 8;      // k-split
    const int n = rb * 64 + (t >> 2);
    const int b = n >> 11, m = n & 2047;

    // z slice: zr[u] = z[c = 4u + j]
    const float* zp = Z + b * 524288 + m;
    float zr[64];
#pragma unroll
    for (int u = 0; u < 64; ++u) zr[u] = zp[(4 * u + j) * 2048];

    const float s1 = S1[n];
    float best = INFINITY;
    int bi = 0;

    const int k0 = ks * KPER;
    for (int k = k0; k < k0 + KPER; ++k) {
        const float* ep = E + k * 256 + j;
        float a = 0.0f;
#pragma unroll
        for (int u = 0; u < 64; ++u) {
            float p = zr[u] * ep[4 * u];
            asm("" : "+v"(p));
            a += p;                      // sequential chain, no fma (contract off + barrier)
        }
        float bs = a + __shfl_xor(a, 1);     // fl(A_j + A_{j^1}) — commutative, same bits all lanes
        float P = bs + __shfl_xor(bs, 2);    // fl((A0+A1)+(A2+A3))
        float d = s1 - 2.0f * P;             // fl(S1 - T), T = 2P exact
        if (d < best) { best = d; bi = k; }
    }
    if (j == 0) part[n * KSPL + ks] = make_float2(best, __int_as_float(bi));
}

// ---------------- merge k-splits (lexicographic: d, then k) ----------------
__global__ void k_merge(const float2* __restrict__ part, int* __restrict__ idxv,
                        float* __restrict__ out) {
    const int n = blockIdx.x * 256 + threadIdx.x;
    float best = INFINITY;
    int bi = 0;
#pragma unroll
    for (int ks = 0; ks < KSPL; ++ks) {
        float2 pr = part[n * KSPL + ks];
        if (pr.x < best) { best = pr.x; bi = __float_as_int(pr.y); }
    }
    idxv[n] = bi;
    out[OUT_IDX + n] = (float)bi;
}

// ---------------- fp64 ||z - e_idx||^2 per row (for the loss) ----------------
__global__ void k_dmin(const float* __restrict__ Z, const float* __restrict__ E,
                       const int* __restrict__ idxv, double* __restrict__ dmin) {
    const int n = blockIdx.x * 4 + (threadIdx.x >> 6);
    const int lane = threadIdx.x & 63;
    const int b = n >> 11, m = n & 2047;
    const int kk = idxv[n];
    const float4 e4 = reinterpret_cast<const float4*>(E + kk * 256)[lane];
    const float* zp = Z + b * 524288 + m;
    double d0 = (double)zp[(4 * lane + 0) * 2048] - (double)e4.x;
    double d1 = (double)zp[(4 * lane + 1) * 2048] - (double)e4.y;
    double d2 = (double)zp[(4 * lane + 2) * 2048] - (double)e4.z;
    double d3 = (double)zp[(4 * lane + 3) * 2048] - (double)e4.w;
    double d = d0 * d0 + d1 * d1 + d2 * d2 + d3 * d3;
    for (int o = 32; o; o >>= 1) d += __shfl_xor(d, o);
    if (lane == 0) dmin[n] = d;
}

// ---------------- gather z_q with LDS transpose ----------------
__global__ void k_gather(const float* __restrict__ emb, const int* __restrict__ idxv,
                         float* __restrict__ out) {
    __shared__ float tile[32][33];
    __shared__ int kidx[32];
    const int blk = blockIdx.x;
    const int ct = blk & 7;
    const int mt = (blk >> 3) & 63;
    const int b = blk >> 9;
    const int t = threadIdx.x, tr = t >> 5, tc = t & 31;

    if (t < 32) kidx[t] = idxv[b * 2048 + mt * 32 + t];
    __syncthreads();
#pragma unroll
    for (int rr = 0; rr < 4; ++rr) {
        int row = tr + rr * 8;                                // m_local
        tile[row][tc] = emb[kidx[row] * 256 + ct * 32 + tc];  // coalesced along c
    }
    __syncthreads();
#pragma unroll
    for (int rr = 0; rr < 4; ++rr) {
        int cl = tr + rr * 8;                                 // c_local
        out[b * 524288 + (ct * 32 + cl) * 2048 + mt * 32 + tc] = tile[tc][cl];
    }
}

// ---------------- final loss reduce ----------------
__global__ void k_loss(const double* __restrict__ dmin, float* __restrict__ out) {
    __shared__ double sm[256];
    double s = 0.0;
    for (int i = threadIdx.x; i < NROWS; i += 256) s += dmin[i];
    sm[threadIdx.x] = s;
    __syncthreads();
    for (int o = 128; o; o >>= 1) {
        if (threadIdx.x < o) sm[threadIdx.x] += sm[threadIdx.x + o];
        __syncthreads();
    }
    if (threadIdx.x == 0)
        out[OUT_LOSS] = (float)(1.25 * sm[0] / 4194304.0);
}

// ---------------- launch ----------------
extern "C" void kernel_launch(void* const* d_in, const int* in_sizes, int n_in,
                              void* d_out, int out_size, void* d_ws, size_t ws_size,
                              hipStream_t stream) {
    const float* Z = (const float*)d_in[0];   // [8,256,8,16,16] fp32
    const float* E = (const float*)d_in[1];   // [8192,256] fp32
    float* out = (float*)d_out;
    char* ws = (char*)d_ws;

    float*  S1   = (float*)ws;                                    // 64 KB
    float2* part = (float2*)(ws + (64 << 10));                    // 512 KB
    double* dmin = (double*)(ws + (64 << 10) + (512 << 10));      // 128 KB
    int*    idxv = (int*)(ws + (64 << 10) + (512 << 10) + (128 << 10)); // 64 KB

    hipLaunchKernelGGL(k_s1,     dim3(64),   dim3(256), 0, stream, Z, S1);
    hipLaunchKernelGGL(k_np,     dim3(1024), dim3(256), 0, stream, Z, E, S1, part);
    hipLaunchKernelGGL(k_merge,  dim3(64),   dim3(256), 0, stream, part, idxv, out);
    hipLaunchKernelGGL(k_dmin,   dim3(4096), dim3(256), 0, stream, Z, E, idxv, dmin);
    hipLaunchKernelGGL(k_gather, dim3(4096), dim3(256), 0, stream, E, idxv, out);
    hipLaunchKernelGGL(k_loss,   dim3(1),    dim3(256), 0, stream, dmin, out);
}